// Round 4
// baseline (413.719 us; speedup 1.0000x reference)
//
#include <hip/hip_runtime.h>
#include <hip/hip_bf16.h>

// PeakBinner: out[b, g*50+o] = relu( sum_k x[b, g*250+k] * W[g,o,k] )
// Round 4: half-window panel reuse. Group g = halves (g: W-k 0..250) and
// (g+1: W-k 250..500). Block stages a 250-col x panel ONCE (1000-B contiguous
// row segments) and feeds TWO group accumulators (accNew=group h, accOld=
// group h-1, register-shifted per half). Chunk = 4 halves / 3 groups ->
// x read 1.3x (was 2x). 31.3 KB LDS -> 5 blocks/CU, 1664 blocks.

constexpr int INPUT = 10000;
constexpr int GS    = 500;
constexpr int STEP  = 250;
constexpr int OPG   = 50;
constexpr int OUTW  = 1950;

constexpr int BM  = 32;
constexpr int NH  = 4;           // halves per chunk (3 groups/chunk, 13 chunks)
constexpr int LDA = 264;         // shorts per A row (256+8): stride 528 B == 4 banks
constexpr int LDB = 72;          // shorts per B row (64+8):  stride 144 B == 4 banks

typedef __attribute__((ext_vector_type(8))) short  short8;
typedef __attribute__((ext_vector_type(4))) float  float4v;

__device__ __forceinline__ unsigned bf2pack(float a, float b) {
    union { float f; unsigned u; } x, y; x.f = a; y.f = b;
    unsigned lo = (x.u + 0x7fffu + ((x.u >> 16) & 1u)) >> 16;
    unsigned hi = (y.u + 0x7fffu + ((y.u >> 16) & 1u)) & 0xffff0000u;
    return hi | lo;
}

__global__ __launch_bounds__(256, 5)
void peak_binner_kernel(const float* __restrict__ x,
                        const float* __restrict__ W,
                        float* __restrict__ out, int batch)
{
    __shared__ __align__(16) short As[BM * LDA];        // 16896 B
    __shared__ __align__(16) short Bs[2 * OPG * LDB];   // 14400 B  (tile1 at +OPG*LDB)

    const int c    = blockIdx.x;          // group chunk 0..12 (groups 3c..3c+2)
    const int m0   = blockIdx.y * BM;
    const int tid  = threadIdx.x;
    const int lane = tid & 63;
    const int wave = tid >> 6;
    const int fm   = lane & 15;
    const int l4   = lane >> 4;
    const int nb   = (wave == 3) ? 34 : wave * 16;   // n-tile rows nb..nb+15 (all real)

    float4v accOld[2] = {{0,0,0,0},{0,0,0,0}};
    float4v accNew[2] = {{0,0,0,0},{0,0,0,0}};

    const int h0 = 3 * c;

    #pragma unroll
    for (int hi = 0; hi < NH; ++hi) {
        const int  h  = h0 + hi;
        const bool p1 = (hi < NH - 1);    // part1: group h   -> accNew
        const bool p2 = (hi > 0);         // part2: group h-1 -> accOld

        __syncthreads();                  // prev half fully consumed

        // ---- stage A panel: 32 rows x 250 cols fp32 -> bf16 (pad to 256) ----
        {
            const float* ap = x + (size_t)m0 * INPUT + (size_t)h * STEP;
            #pragma unroll
            for (int bb = 0; bb < 2; ++bb) {
                float2 v[8];
                #pragma unroll
                for (int j = 0; j < 8; ++j) {       // batch 8 loads -> MLP
                    const int f = tid + 256 * (bb * 8 + j);
                    const int row = f >> 7, cp = f & 127;
                    v[j] = (cp < 125) ? *(const float2*)(ap + (size_t)row * INPUT + 2 * cp)
                                      : float2{0.f, 0.f};
                }
                #pragma unroll
                for (int j = 0; j < 8; ++j) {
                    const int f = tid + 256 * (bb * 8 + j);
                    const int row = f >> 7, cp = f & 127;
                    *(unsigned*)&As[row * LDA + 2 * cp] = bf2pack(v[j].x, v[j].y);
                }
            }
        }

        // ---- 4 K-slices of 64 (250 valid, zero-padded) ----
        #pragma unroll
        for (int s = 0; s < 4; ++s) {
            if (s) __syncthreads();       // compute(s-1) done reading Bs

            // stage B slice: tile0 = W[h,:,64s..], tile1 = W[h-1,:,250+64s..]
            if (p1) {
                const float* wp = W + (size_t)h * OPG * GS;
                #pragma unroll
                for (int j = 0; j < 7; ++j) {
                    const int f = tid + 256 * j;
                    if (f < 1600) {
                        const int row = f >> 5, cp = f & 31, k = s * 64 + 2 * cp;
                        float2 v = (k + 2 <= STEP) ? *(const float2*)(wp + row * GS + k)
                                                   : float2{0.f, 0.f};
                        *(unsigned*)&Bs[row * LDB + 2 * cp] = bf2pack(v.x, v.y);
                    }
                }
            }
            if (p2) {
                const float* wp = W + (size_t)(h - 1) * OPG * GS + STEP;
                #pragma unroll
                for (int j = 0; j < 7; ++j) {
                    const int f = tid + 256 * j;
                    if (f < 1600) {
                        const int row = f >> 5, cp = f & 31, k = s * 64 + 2 * cp;
                        float2 v = (k + 2 <= STEP) ? *(const float2*)(wp + row * GS + k)
                                                   : float2{0.f, 0.f};
                        *(unsigned*)&Bs[OPG * LDB + row * LDB + 2 * cp] = bf2pack(v.x, v.y);
                    }
                }
            }
            __syncthreads();

            // ---- compute: A frags shared by all waves; B per wave n-tile ----
            short8 a[2][2];
            #pragma unroll
            for (int mt = 0; mt < 2; ++mt)
                #pragma unroll
                for (int kk = 0; kk < 2; ++kk)
                    a[mt][kk] = *(const short8*)&As[(mt * 16 + fm) * LDA + s * 64 + kk * 32 + l4 * 8];
            if (p1) {
                #pragma unroll
                for (int kk = 0; kk < 2; ++kk) {
                    const short8 b = *(const short8*)&Bs[(nb + fm) * LDB + kk * 32 + l4 * 8];
                    accNew[0] = __builtin_amdgcn_mfma_f32_16x16x32_bf16(a[0][kk], b, accNew[0], 0, 0, 0);
                    accNew[1] = __builtin_amdgcn_mfma_f32_16x16x32_bf16(a[1][kk], b, accNew[1], 0, 0, 0);
                }
            }
            if (p2) {
                #pragma unroll
                for (int kk = 0; kk < 2; ++kk) {
                    const short8 b = *(const short8*)&Bs[OPG * LDB + (nb + fm) * LDB + kk * 32 + l4 * 8];
                    accOld[0] = __builtin_amdgcn_mfma_f32_16x16x32_bf16(a[0][kk], b, accOld[0], 0, 0, 0);
                    accOld[1] = __builtin_amdgcn_mfma_f32_16x16x32_bf16(a[1][kk], b, accOld[1], 0, 0, 0);
                }
            }
        }

        // ---- end of half: group h-1 complete -> relu + store ----
        if (p2) {
            const int g = h - 1;
            // C/D layout: col = lane&15, row = (lane>>4)*4 + reg
            const bool cval = (wave < 3) || (fm >= 14);   // wave3 stores cols 48,49 only
            if (cval) {
                const int col = g * OPG + nb + fm;
                #pragma unroll
                for (int mt = 0; mt < 2; ++mt)
                    #pragma unroll
                    for (int reg = 0; reg < 4; ++reg) {
                        const int row = m0 + mt * 16 + l4 * 4 + reg;
                        out[(size_t)row * OUTW + col] = fmaxf(accOld[mt][reg], 0.f);
                    }
            }
        }
        // shift accumulators: group h becomes the finishing one
        accOld[0] = accNew[0]; accOld[1] = accNew[1];
        accNew[0] = float4v{0,0,0,0}; accNew[1] = float4v{0,0,0,0};
    }
}

extern "C" void kernel_launch(void* const* d_in, const int* in_sizes, int n_in,
                              void* d_out, int out_size, void* d_ws, size_t ws_size,
                              hipStream_t stream) {
    const float* x = (const float*)d_in[0];   // (batch, 10000) fp32
    const float* W = (const float*)d_in[1];   // (39, 50, 500) fp32
    float* out     = (float*)d_out;           // (batch, 1950) fp32

    const int batch = in_sizes[0] / INPUT;    // 4096
    dim3 grid(13, batch / BM);                // 13 chunks x 128 row-tiles = 1664
    peak_binner_kernel<<<grid, dim3(256), 0, stream>>>(x, W, out, batch);
}

// Round 5
// 280.832 us; speedup vs baseline: 1.4732x; 1.4732x over previous
//
#include <hip/hip_runtime.h>
#include <hip/hip_bf16.h>

// PeakBinner: out[b, g*50+o] = relu( sum_k x[b, g*250+k] * W[g,o,k] )
// Round 5: one-barrier blocks. W pre-converted to bf16 (K padded to 512,
// zero-filled) in a module __device__ buffer by a prep kernel; main kernel
// stages only A (32 rows x 500 fp32 as contiguous 2000-B row reads, batched
// 8-deep for MLP, bf16-converted into LDS), ONE __syncthreads, then a
// barrier-free fully-unrolled K loop: ds_read_b128 (A) + L2-hit
// global_load_dwordx4 (B) + MFMA. 33.3 KB LDS -> 4 blocks/CU.

constexpr int INPUT  = 10000;
constexpr int GROUPS = 39;
constexpr int GS     = 500;
constexpr int STEP   = 250;
constexpr int OPG    = 50;
constexpr int OUTW   = 1950;
constexpr int KP     = 512;          // padded K
constexpr int BM     = 32;
constexpr int LDA    = KP + 8;       // shorts; 1040-B row stride (4 banks mod 32)

__device__ __hip_bfloat16 Wb[GROUPS * OPG * KP];   // 2.0 MB, L2-resident

typedef __attribute__((ext_vector_type(8))) short  short8;
typedef __attribute__((ext_vector_type(4))) float  float4v;

__device__ __forceinline__ unsigned bf2pack(float a, float b) {
    union { float f; unsigned u; } x, y; x.f = a; y.f = b;
    unsigned lo = (x.u + 0x7fffu + ((x.u >> 16) & 1u)) >> 16;
    unsigned hi = (y.u + 0x7fffu + ((y.u >> 16) & 1u)) & 0xffff0000u;
    return hi | lo;
}

__global__ void prep_w(const float* __restrict__ W) {
    const int slot = blockIdx.x * 256 + threadIdx.x;     // dword slots
    if (slot >= GROUPS * OPG * (KP / 2)) return;
    const int go = slot / (KP / 2);
    const int k  = (slot - go * (KP / 2)) * 2;
    float2 v = {0.f, 0.f};
    if (k < GS) v = *(const float2*)(W + (size_t)go * GS + k);
    ((unsigned*)Wb)[slot] = bf2pack(v.x, v.y);
}

__global__ __launch_bounds__(256, 4)
void peak_binner_kernel(const float* __restrict__ x,
                        float* __restrict__ out, int batch)
{
    __shared__ __align__(16) short As[BM * LDA];   // 33,280 B

    const int g    = blockIdx.x;
    const int m0   = blockIdx.y * BM;
    const int tid  = threadIdx.x;
    const int lane = tid & 63;
    const int wave = tid >> 6;
    const int fm   = lane & 15;
    const int l4   = lane >> 4;
    const int nb   = (wave == 3) ? 34 : wave * 16;   // wave n-rows nb..nb+15

    // ---- stage A: 32 rows x 500 fp32 -> bf16, cols 500..511 zeroed ----
    // iteration it = row; thread tid handles float2 at col 2*tid (tid>=250 -> 0)
    const bool lvalid = (tid < STEP);                // 2*tid < 500
    #pragma unroll
    for (int bb = 0; bb < 4; ++bb) {
        float2 v[8];
        #pragma unroll
        for (int j = 0; j < 8; ++j) {                // 8 loads in flight
            const int it = bb * 8 + j;
            const int gr = min(m0 + it, batch - 1);
            v[j] = lvalid ? *(const float2*)(x + (size_t)gr * INPUT + g * STEP + 2 * tid)
                          : float2{0.f, 0.f};
        }
        #pragma unroll
        for (int j = 0; j < 8; ++j) {
            const int it = bb * 8 + j;
            *(unsigned*)&As[it * LDA + 2 * tid] = bf2pack(v[j].x, v[j].y);
        }
    }

    float4v acc[2] = {{0,0,0,0},{0,0,0,0}};
    // B fragment base: Wb[g][nb+fm][l4*8 + kk*32], one 16-B load per k-step
    const __hip_bfloat16* wp = Wb + ((size_t)g * OPG + nb + fm) * KP + l4 * 8;

    __syncthreads();                                 // the only barrier

    // ---- barrier-free K loop: 16 steps of 32 ----
    #pragma unroll
    for (int kk = 0; kk < 16; ++kk) {
        const short8 b  = *(const short8*)(wp + kk * 32);
        const short8 a0 = *(const short8*)&As[fm        * LDA + kk * 32 + l4 * 8];
        const short8 a1 = *(const short8*)&As[(16 + fm) * LDA + kk * 32 + l4 * 8];
        acc[0] = __builtin_amdgcn_mfma_f32_16x16x32_bf16(a0, b, acc[0], 0, 0, 0);
        acc[1] = __builtin_amdgcn_mfma_f32_16x16x32_bf16(a1, b, acc[1], 0, 0, 0);
    }

    // ---- epilogue: C/D col=lane&15, row=(lane>>4)*4+reg; relu + store ----
    // wave3 computes cols 34..49 but stores only 48,49 (waves 0-2 cover 0..47)
    if (wave < 3 || fm >= 14) {
        const int col = g * OPG + nb + fm;
        #pragma unroll
        for (int mt = 0; mt < 2; ++mt)
            #pragma unroll
            for (int reg = 0; reg < 4; ++reg) {
                const int row = m0 + mt * 16 + l4 * 4 + reg;
                if (row < batch)
                    out[(size_t)row * OUTW + col] = fmaxf(acc[mt][reg], 0.f);
            }
    }
}

extern "C" void kernel_launch(void* const* d_in, const int* in_sizes, int n_in,
                              void* d_out, int out_size, void* d_ws, size_t ws_size,
                              hipStream_t stream) {
    const float* x = (const float*)d_in[0];   // (batch, 10000) fp32
    const float* W = (const float*)d_in[1];   // (39, 50, 500) fp32
    float* out     = (float*)d_out;           // (batch, 1950) fp32

    const int batch = in_sizes[0] / INPUT;    // 4096

    // prep: W fp32 -> Wb bf16 (K padded to 512, zeros beyond 500)
    const int slots = GROUPS * OPG * (KP / 2);            // 499,200
    prep_w<<<(slots + 255) / 256, 256, 0, stream>>>(W);

    dim3 grid(GROUPS, (batch + BM - 1) / BM);             // 39 x 128 = 4992
    peak_binner_kernel<<<grid, dim3(256), 0, stream>>>(x, out, batch);
}